// Round 8
// baseline (28.312 us; speedup 1.0000x reference)
//
#include <hip/hip_runtime.h>
#include <hip/hip_bf16.h>
#include <stdint.h>

#define BLOCK 256
#define NBLK  512
#define SLOT  8   // doubles per block slot (64 B): 5 partials + pad

// Channel constant: NOISE_RATE from the reference (kop is a deterministic
// function of it; hardcoded to avoid device-dtype ambiguity).
#define G_NOISE 0.233

// ---- order-8 Gauss-Legendre nodes/weights mapped to [0,1] (exact leggauss(8)/2) ----
#define GL_T0 0.019855071751231856
#define GL_T1 0.10166676129318663
#define GL_T2 0.23723379504183550
#define GL_T3 0.40828267875217510
#define GL_T4 0.59171732124782490
#define GL_T5 0.76276620495816449
#define GL_T6 0.89833323870681337
#define GL_T7 0.98014492824876811
#define GL_W0 0.05061426814518813
#define GL_W1 0.11119051722668723
#define GL_W2 0.15685332293894364
#define GL_W3 0.18134107081135099

// F(lam) = lam * glog(lam), glog = 2^6 * sum_j w_j x/(1+t_j x), x = lam^(1/64)-1.
// Fast form validated bit-exact vs harness ref in R6/R7 (absmax 0.0).
__device__ __forceinline__ float F_pade_fast(float lam) {
    if (!(lam > 0.0f)) return 0.0f;
    const float TJ[8] = {(float)GL_T0,(float)GL_T1,(float)GL_T2,(float)GL_T3,
                         (float)GL_T4,(float)GL_T5,(float)GL_T6,(float)GL_T7};
    const float WJ[8] = {(float)GL_W0,(float)GL_W1,(float)GL_W2,(float)GL_W3,
                         (float)GL_W3,(float)GL_W2,(float)GL_W1,(float)GL_W0};
    float x = __expf(__logf(lam) * 0.015625f) - 1.0f;   // lam^(1/64) - 1
    float s = 0.0f;
#pragma unroll
    for (int j = 0; j < 8; ++j)
        s += __fdividef(WJ[j] * x, fmaf(TJ[j], x, 1.0f));
    return 64.0f * lam * s;
}

__device__ __forceinline__ double F_pade_d(double lam) {
    if (!(lam > 0.0)) return 0.0;
    const double TJ[8] = {GL_T0,GL_T1,GL_T2,GL_T3,GL_T4,GL_T5,GL_T6,GL_T7};
    const double WJ[8] = {GL_W0,GL_W1,GL_W2,GL_W3,GL_W3,GL_W2,GL_W1,GL_W0};
    double x = expm1(log(lam) * 0.015625);
    double s = 0.0;
#pragma unroll
    for (int j = 0; j < 8; ++j)
        s += WJ[j] * x / fma(TJ[j], x, 1.0);
    return 64.0 * lam * s;
}

// per-sample: given coeff c and raw 2x2 state s, produce the 5 reduction terms
__device__ __forceinline__ void sample_terms(float c, float4 s, float gg,
                                             bool valid, float out[5]) {
    float t = __logf(1.0f + __expf(c));           // softplus (c in [-1,1], safe)
    if (!valid) t = 0.0f;                         // masked lane: all terms vanish
    float n2 = fmaf(s.x, s.x, fmaf(s.y, s.y, fmaf(s.z, s.z, s.w * s.w)));
    float inv = __fdividef(1.0f, n2);
    float q  = (s.z * s.z + s.w * s.w) * inv;     // |psi1|^2
    float cr = (s.x * s.z + s.y * s.w) * inv;     // Re(psi0 conj(psi1))
    float ci = (s.y * s.z - s.x * s.w) * inv;     // Im(psi0 conj(psi1))
    float det = gg * q * q;                       // det(sigma_n), in [0, g(1-g)]
    float disc = sqrtf(0.25f - det);              // det <= 0.1787 -> arg >= 0.071
    float lp = 0.5f + disc;
    float lm = __fdividef(det, lp);
    float E = -(F_pade_fast(lp) + F_pade_fast(lm));
    out[0] = t; out[1] = t * q; out[2] = t * cr; out[3] = t * ci; out[4] = t * E;
}

__global__ __launch_bounds__(BLOCK) void fused_kernel(
    const float* __restrict__ coeff, const float4* __restrict__ state,
    double* __restrict__ ws, unsigned long long* __restrict__ counter,
    float* __restrict__ out, int N)
{
    const float gg = (float)(G_NOISE * (1.0 - G_NOISE));   // g*(1-g)
    const int tid = blockIdx.x * BLOCK + threadIdx.x;      // 0..131071
    const int T = NBLK * BLOCK;                            // 131072

    // ---- producer: 4 independent sample chains/thread (R7-validated) ----
    const int i1 = tid + T, i2 = tid + 2 * T, i3 = tid + 3 * T;
    const bool v3 = (i3 < N);
    float  c0 = coeff[tid],  c1 = coeff[i1],  c2 = coeff[i2];
    float4 s0 = state[tid],  s1 = state[i1],  s2 = state[i2];
    float  c3 = v3 ? coeff[i3] : 0.0f;
    float4 s3 = v3 ? state[i3] : make_float4(1.f, 0.f, 0.f, 0.f);

    float r0[5], r1[5], r2[5], r3[5];
    sample_terms(c0, s0, gg, true, r0);
    sample_terms(c1, s1, gg, true, r1);
    sample_terms(c2, s2, gg, true, r2);
    sample_terms(c3, s3, gg, v3,   r3);

    double acc[5];
#pragma unroll
    for (int k = 0; k < 5; ++k)
        acc[k] = ((double)r0[k] + (double)r1[k]) + ((double)r2[k] + (double)r3[k]);

    // safety net for N > 4*T (dead for N=500000)
    for (int i = tid + 4 * T; i < N; i += T) {
        float rr[5];
        sample_terms(coeff[i], state[i], gg, true, rr);
#pragma unroll
        for (int k = 0; k < 5; ++k) acc[k] += (double)rr[k];
    }

    __shared__ double smem[BLOCK / 64][5];
    __shared__ int last_flag;
    const int lane = threadIdx.x & 63, wave = threadIdx.x >> 6;
#pragma unroll
    for (int k = 0; k < 5; ++k) {
        double v = acc[k];
        for (int o = 32; o > 0; o >>= 1) v += __shfl_down(v, o, 64);
        if (lane == 0) smem[wave][k] = v;
    }
    __syncthreads();
    if (threadIdx.x == 0) {
        double* slot = ws + (size_t)blockIdx.x * SLOT;
#pragma unroll
        for (int k = 0; k < 5; ++k) {
            double v = smem[0][k] + smem[1][k] + smem[2][k] + smem[3][k];
            __hip_atomic_store(&slot[k], v, __ATOMIC_RELAXED, __HIP_MEMORY_SCOPE_AGENT);
        }
        // release RMW: slot stores visible device-wide before the count bumps.
        // old == NBLK-1  <=>  all other blocks' slots are already visible.
        unsigned long long old = __hip_atomic_fetch_add(
            counter, 1ull, __ATOMIC_ACQ_REL, __HIP_MEMORY_SCOPE_AGENT);
        last_flag = (old == (unsigned long long)(NBLK - 1)) ? 1 : 0;
    }
    __syncthreads();
    if (!last_flag) return;

    // ---- finalize (the unique last block; no waiting needed) ----
    // Arithmetic identical to R7's final_kernel -> bit-identical result.
    const int t = threadIdx.x;
    double v[5];
#pragma unroll
    for (int k = 0; k < 5; ++k)
        v[k] = __hip_atomic_load(ws + (size_t)t * SLOT + k,
                                 __ATOMIC_RELAXED, __HIP_MEMORY_SCOPE_AGENT)
             + __hip_atomic_load(ws + (size_t)(t + BLOCK) * SLOT + k,
                                 __ATOMIC_RELAXED, __HIP_MEMORY_SCOPE_AGENT);

    __syncthreads();   // smem reuse
#pragma unroll
    for (int k = 0; k < 5; ++k) {
        double x = v[k];
        for (int o = 32; o > 0; o >>= 1) x += __shfl_down(x, o, 64);
        if (lane == 0) smem[wave][k] = x;
    }
    __syncthreads();
    if (t == 0) {
        double T_  = smem[0][0] + smem[1][0] + smem[2][0] + smem[3][0];
        double B   = smem[0][1] + smem[1][1] + smem[2][1] + smem[3][1];
        double Cr  = smem[0][2] + smem[1][2] + smem[2][2] + smem[3][2];
        double Ci  = smem[0][3] + smem[1][3] + smem[2][3] + smem[3][3];
        double D   = smem[0][4] + smem[1][4] + smem[2][4] + smem[3][4];

        const double b2 = G_NOISE;          // g
        const double a2 = 1.0 - G_NOISE;    // 1-g
        double r11 = B / T_;                           // rho_11
        double r00 = 1.0 - r11;
        double c2  = (Cr * Cr + Ci * Ci) / (T_ * T_);  // |rho_01|^2
        double det = (r00 + b2 * r11) * (a2 * r11) - a2 * c2;
        double disc = 0.25 - det;
        disc = disc > 0.0 ? sqrt(disc) : 0.0;
        double lp = 0.5 + disc;
        double lm = lp > 0.0 ? det / lp : 0.0;
        double S_out = -(F_pade_d(lp) + F_pade_d(lm));
        double res = -S_out + D / T_;                  // -(S(rho_out) - sum coeff*S(sigma))

        out[0] = (float)res;                           // reference output dtype: float
    }
}

extern "C" void kernel_launch(void* const* d_in, const int* in_sizes, int n_in,
                              void* d_out, int out_size, void* d_ws, size_t ws_size,
                              hipStream_t stream) {
    const float*  coeff = (const float*)d_in[0];
    const float4* state = (const float4*)d_in[1];   // 4 floats per sample, 16B aligned
    const int N = in_sizes[0];
    double* ws = (double*)d_ws;                     // NBLK*SLOT doubles = 32768 B
    unsigned long long* counter =
        (unsigned long long*)((char*)d_ws + (size_t)NBLK * SLOT * sizeof(double));

    // zero the arrival counter every launch (graph-legal memset node)
    hipMemsetAsync(counter, 0, sizeof(unsigned long long), stream);
    fused_kernel<<<NBLK, BLOCK, 0, stream>>>(coeff, state, ws, counter,
                                             (float*)d_out, N);
}

// Round 9
// 14.092 us; speedup vs baseline: 2.0091x; 2.0091x over previous
//
#include <hip/hip_runtime.h>
#include <hip/hip_bf16.h>
#include <stdint.h>

#define BLOCK 256
#define NBLK  512   // partials: NBLK*5 doubles = 20480 B of d_ws

// Channel constant: NOISE_RATE from the reference (kop is a deterministic
// function of it; hardcoded to avoid device-dtype ambiguity).
#define G_NOISE 0.233

// ---- order-8 Gauss-Legendre nodes/weights mapped to [0,1] (exact leggauss(8)/2) ----
#define GL_T0 0.019855071751231856
#define GL_T1 0.10166676129318663
#define GL_T2 0.23723379504183550
#define GL_T3 0.40828267875217510
#define GL_T4 0.59171732124782490
#define GL_T5 0.76276620495816449
#define GL_T6 0.89833323870681337
#define GL_T7 0.98014492824876811
#define GL_W0 0.05061426814518813
#define GL_W1 0.11119051722668723
#define GL_W2 0.15685332293894364
#define GL_W3 0.18134107081135099

// Exact replica of psd_logm's scalar action (6 sqrtms + GL-8 Pade), f64.
// Used once per launch in the finalize path.
__device__ __forceinline__ double F_pade_d(double lam) {
    if (!(lam > 0.0)) return 0.0;
    const double TJ[8] = {GL_T0,GL_T1,GL_T2,GL_T3,GL_T4,GL_T5,GL_T6,GL_T7};
    const double WJ[8] = {GL_W0,GL_W1,GL_W2,GL_W3,GL_W3,GL_W2,GL_W1,GL_W0};
    double x = expm1(log(lam) * 0.015625);
    double s = 0.0;
#pragma unroll
    for (int j = 0; j < 8; ++j)
        s += WJ[j] * x / fma(TJ[j], x, 1.0);
    return 64.0 * lam * s;
}

// per-sample: given coeff c and raw 2x2 state s, produce the 5 reduction terms.
// Entropy via direct -lam*ln(lam): for lam in (0,1] the reference's
// 6-sqrtm + GL-8 Pade logm equals exact ln to <1e-9 in the product lam*ln(lam)
// (x = lam^(1/64)-1 stays in (-0.28, 0], where the [8/8] Pade is ~1e-10 rel),
// so this matches the R7-validated path (absmax 0.0) at ~1/4 the instructions.
__device__ __forceinline__ void sample_terms(float c, float4 s, float gg,
                                             bool valid, float out[5]) {
    float t = __logf(1.0f + __expf(c));           // softplus (c in [-1,1], safe)
    if (!valid) t = 0.0f;                         // masked lane: all terms vanish
    float n2 = fmaf(s.x, s.x, fmaf(s.y, s.y, fmaf(s.z, s.z, s.w * s.w)));
    float inv = __fdividef(1.0f, n2);
    float q  = (s.z * s.z + s.w * s.w) * inv;     // |psi1|^2
    float cr = (s.x * s.z + s.y * s.w) * inv;     // Re(psi0 conj(psi1))
    float ci = (s.y * s.z - s.x * s.w) * inv;     // Im(psi0 conj(psi1))
    float det = gg * q * q;                       // det(sigma_n), in [0, g(1-g)]
    float disc = sqrtf(0.25f - det);              // det <= 0.1787 -> arg >= 0.071
    float lp = 0.5f + disc;                       // lam+ in [0.5, 1]
    float lm = __fdividef(det, lp);               // lam- (stable for tiny det)
    float Ep = lp * __logf(lp);                   // lp >= 0.5: log finite
    float Em = (lm > 1e-30f) ? lm * __logf(lm) : 0.0f;  // guard 0*(-inf)
    float E = -(Ep + Em);                         // vne(sigma_n)
    out[0] = t; out[1] = t * q; out[2] = t * cr; out[3] = t * ci; out[4] = t * E;
}

__global__ __launch_bounds__(BLOCK) void reduce_kernel(
    const float* __restrict__ coeff, const float4* __restrict__ state,
    double* __restrict__ partial, int N)
{
    const float gg = (float)(G_NOISE * (1.0 - G_NOISE));   // g*(1-g)
    const int tid = blockIdx.x * BLOCK + threadIdx.x;      // 0..131071
    const int T = NBLK * BLOCK;                            // 131072

    // 4 samples/thread, 4 independent chains (N=500000: chains 0-2 always
    // valid since 3*T-1 < N; chain 3 masks at tid >= N-3*T).
    const int i1 = tid + T, i2 = tid + 2 * T, i3 = tid + 3 * T;
    const bool v3 = (i3 < N);
    float  c0 = coeff[tid],  c1 = coeff[i1],  c2 = coeff[i2];
    float4 s0 = state[tid],  s1 = state[i1],  s2 = state[i2];
    float  c3 = v3 ? coeff[i3] : 0.0f;
    float4 s3 = v3 ? state[i3] : make_float4(1.f, 0.f, 0.f, 0.f);

    float r0[5], r1[5], r2[5], r3[5];
    sample_terms(c0, s0, gg, true, r0);
    sample_terms(c1, s1, gg, true, r1);
    sample_terms(c2, s2, gg, true, r2);
    sample_terms(c3, s3, gg, v3,   r3);

    double acc[5];
#pragma unroll
    for (int k = 0; k < 5; ++k)
        acc[k] = ((double)r0[k] + (double)r1[k]) + ((double)r2[k] + (double)r3[k]);

    // safety net for N > 4*T (dead for N=500000)
    for (int i = tid + 4 * T; i < N; i += T) {
        float rr[5];
        sample_terms(coeff[i], state[i], gg, true, rr);
#pragma unroll
        for (int k = 0; k < 5; ++k) acc[k] += (double)rr[k];
    }

    __shared__ double smem[BLOCK / 64][5];
    const int lane = threadIdx.x & 63, wave = threadIdx.x >> 6;
#pragma unroll
    for (int k = 0; k < 5; ++k) {
        double v = acc[k];
        for (int o = 32; o > 0; o >>= 1) v += __shfl_down(v, o, 64);
        if (lane == 0) smem[wave][k] = v;
    }
    __syncthreads();
    if (threadIdx.x == 0) {
#pragma unroll
        for (int k = 0; k < 5; ++k)
            partial[blockIdx.x * 5 + k] =
                smem[0][k] + smem[1][k] + smem[2][k] + smem[3][k];
    }
}

__global__ __launch_bounds__(BLOCK) void final_kernel(
    const double* __restrict__ partial, float* __restrict__ out)
{
    const int t = threadIdx.x;
    double v[5];
#pragma unroll
    for (int k = 0; k < 5; ++k)
        v[k] = partial[t * 5 + k] + partial[(t + BLOCK) * 5 + k];  // NBLK = 2*BLOCK

    __shared__ double smem[BLOCK / 64][5];
    const int lane = t & 63, wave = t >> 6;
#pragma unroll
    for (int k = 0; k < 5; ++k) {
        double x = v[k];
        for (int o = 32; o > 0; o >>= 1) x += __shfl_down(x, o, 64);
        if (lane == 0) smem[wave][k] = x;
    }
    __syncthreads();
    if (t == 0) {
        double T  = smem[0][0] + smem[1][0] + smem[2][0] + smem[3][0];
        double B  = smem[0][1] + smem[1][1] + smem[2][1] + smem[3][1];
        double Cr = smem[0][2] + smem[1][2] + smem[2][2] + smem[3][2];
        double Ci = smem[0][3] + smem[1][3] + smem[2][3] + smem[3][3];
        double D  = smem[0][4] + smem[1][4] + smem[2][4] + smem[3][4];

        const double b2 = G_NOISE;          // g
        const double a2 = 1.0 - G_NOISE;    // 1-g
        double r11 = B / T;                          // rho_11
        double r00 = 1.0 - r11;
        double c2  = (Cr * Cr + Ci * Ci) / (T * T);  // |rho_01|^2
        double det = (r00 + b2 * r11) * (a2 * r11) - a2 * c2;
        double disc = 0.25 - det;
        disc = disc > 0.0 ? sqrt(disc) : 0.0;
        double lp = 0.5 + disc;
        double lm = lp > 0.0 ? det / lp : 0.0;
        double S_out = -(F_pade_d(lp) + F_pade_d(lm));
        double res = -S_out + D / T;                 // -(S(rho_out) - sum coeff*S(sigma))

        out[0] = (float)res;                         // reference output dtype: float
    }
}

extern "C" void kernel_launch(void* const* d_in, const int* in_sizes, int n_in,
                              void* d_out, int out_size, void* d_ws, size_t ws_size,
                              hipStream_t stream) {
    const float*  coeff = (const float*)d_in[0];
    const float4* state = (const float4*)d_in[1];   // 4 floats per sample, 16B aligned
    const int N = in_sizes[0];
    double* partial = (double*)d_ws;                // NBLK*5 doubles = 20480 B

    reduce_kernel<<<NBLK, BLOCK, 0, stream>>>(coeff, state, partial, N);
    final_kernel<<<1, BLOCK, 0, stream>>>(partial, (float*)d_out);
}

// Round 10
// 13.963 us; speedup vs baseline: 2.0276x; 1.0092x over previous
//
#include <hip/hip_runtime.h>
#include <hip/hip_bf16.h>
#include <stdint.h>

#define BLOCK 256
#define NBLK  512   // partials: NBLK*5 doubles = 20480 B of d_ws

// Channel constant: NOISE_RATE from the reference (kop is a deterministic
// function of it; hardcoded to avoid device-dtype ambiguity).
#define G_NOISE 0.233

// ---- order-8 Gauss-Legendre nodes/weights mapped to [0,1] (exact leggauss(8)/2) ----
#define GL_T0 0.019855071751231856
#define GL_T1 0.10166676129318663
#define GL_T2 0.23723379504183550
#define GL_T3 0.40828267875217510
#define GL_T4 0.59171732124782490
#define GL_T5 0.76276620495816449
#define GL_T6 0.89833323870681337
#define GL_T7 0.98014492824876811
#define GL_W0 0.05061426814518813
#define GL_W1 0.11119051722668723
#define GL_W2 0.15685332293894364
#define GL_W3 0.18134107081135099

// Exact replica of psd_logm's scalar action (6 sqrtms + GL-8 Pade), f64.
// Used once per launch in the finalize path.
__device__ __forceinline__ double F_pade_d(double lam) {
    if (!(lam > 0.0)) return 0.0;
    const double TJ[8] = {GL_T0,GL_T1,GL_T2,GL_T3,GL_T4,GL_T5,GL_T6,GL_T7};
    const double WJ[8] = {GL_W0,GL_W1,GL_W2,GL_W3,GL_W3,GL_W2,GL_W1,GL_W0};
    double x = expm1(log(lam) * 0.015625);
    double s = 0.0;
#pragma unroll
    for (int j = 0; j < 8; ++j)
        s += WJ[j] * x / fma(TJ[j], x, 1.0);
    return 64.0 * lam * s;
}

// per-sample terms; entropy via -lam*ln(lam) (R9-validated: matches the
// reference's 6-sqrtm+GL8-Pade logm to <1e-9 on lam in (0,1]; absmax 0.0).
__device__ __forceinline__ void sample_terms(float c, float4 s, float gg,
                                             float out[5]) {
    float t = __logf(1.0f + __expf(c));           // softplus (c in [-1,1], safe)
    float n2 = fmaf(s.x, s.x, fmaf(s.y, s.y, fmaf(s.z, s.z, s.w * s.w)));
    float inv = __fdividef(1.0f, n2);
    float q  = (s.z * s.z + s.w * s.w) * inv;     // |psi1|^2
    float cr = (s.x * s.z + s.y * s.w) * inv;     // Re(psi0 conj(psi1))
    float ci = (s.y * s.z - s.x * s.w) * inv;     // Im(psi0 conj(psi1))
    float det = gg * q * q;                       // det(sigma_n), in [0, g(1-g)]
    float disc = sqrtf(0.25f - det);              // det <= 0.1787 -> arg >= 0.071
    float lp = 0.5f + disc;                       // lam+ in [0.5, 1]
    float lm = __fdividef(det, lp);               // lam- (stable for tiny det)
    float Ep = lp * __logf(lp);
    float Em = (lm > 1e-30f) ? lm * __logf(lm) : 0.0f;  // guard 0*(-inf)
    float E = -(Ep + Em);                         // vne(sigma_n)
    out[0] = t; out[1] = t * q; out[2] = t * cr; out[3] = t * ci; out[4] = t * E;
}

__global__ __launch_bounds__(BLOCK) void reduce_kernel(
    const float* __restrict__ coeff, const float4* __restrict__ state,
    double* __restrict__ partial, int N)
{
    const float gg = (float)(G_NOISE * (1.0 - G_NOISE));   // g*(1-g)
    const int tid = blockIdx.x * BLOCK + threadIdx.x;      // 0..131071
    const int t4 = tid * 4;                                // 4 consecutive samples

    float sum[5] = {0.f, 0.f, 0.f, 0.f, 0.f};
    if (t4 + 3 < N) {
        // fast path (blocks 0..487 entirely): vector coeff load, 4 states
        float4 cv = *reinterpret_cast<const float4*>(coeff + t4);  // 16B aligned
        float4 s0 = state[t4], s1 = state[t4 + 1],
               s2 = state[t4 + 2], s3 = state[t4 + 3];
        float r0[5], r1[5], r2[5], r3[5];
        sample_terms(cv.x, s0, gg, r0);
        sample_terms(cv.y, s1, gg, r1);
        sample_terms(cv.z, s2, gg, r2);
        sample_terms(cv.w, s3, gg, r3);
#pragma unroll
        for (int k = 0; k < 5; ++k)
            sum[k] = (r0[k] + r1[k]) + (r2[k] + r3[k]);
    } else {
        // tail path (24 boundary blocks): per-sample masked scalar loads
        for (int j = 0; j < 4; ++j) {
            const int i = t4 + j;
            if (i < N) {
                float rr[5];
                sample_terms(coeff[i], state[i], gg, rr);
#pragma unroll
                for (int k = 0; k < 5; ++k) sum[k] += rr[k];
            }
        }
    }
    // safety net for N > 4*total_threads (dead for N=500000)
    for (int i = t4 + 4 * NBLK * BLOCK; i < N; ++i) {
        float rr[5];
        sample_terms(coeff[i], state[i], gg, rr);
#pragma unroll
        for (int k = 0; k < 5; ++k) sum[k] += rr[k];
    }

    __shared__ double smem[BLOCK / 64][5];
    const int lane = threadIdx.x & 63, wave = threadIdx.x >> 6;
#pragma unroll
    for (int k = 0; k < 5; ++k) {
        double v = (double)sum[k];                 // single f32->f64 per channel
        for (int o = 32; o > 0; o >>= 1) v += __shfl_down(v, o, 64);
        if (lane == 0) smem[wave][k] = v;
    }
    __syncthreads();
    if (threadIdx.x == 0) {
#pragma unroll
        for (int k = 0; k < 5; ++k)
            partial[blockIdx.x * 5 + k] =
                smem[0][k] + smem[1][k] + smem[2][k] + smem[3][k];
    }
}

__global__ __launch_bounds__(BLOCK) void final_kernel(
    const double* __restrict__ partial, float* __restrict__ out)
{
    const int t = threadIdx.x;
    double v[5];
#pragma unroll
    for (int k = 0; k < 5; ++k)
        v[k] = partial[t * 5 + k] + partial[(t + BLOCK) * 5 + k];  // NBLK = 2*BLOCK

    __shared__ double smem[BLOCK / 64][5];
    const int lane = t & 63, wave = t >> 6;
#pragma unroll
    for (int k = 0; k < 5; ++k) {
        double x = v[k];
        for (int o = 32; o > 0; o >>= 1) x += __shfl_down(x, o, 64);
        if (lane == 0) smem[wave][k] = x;
    }
    __syncthreads();
    if (t == 0) {
        double T  = smem[0][0] + smem[1][0] + smem[2][0] + smem[3][0];
        double B  = smem[0][1] + smem[1][1] + smem[2][1] + smem[3][1];
        double Cr = smem[0][2] + smem[1][2] + smem[2][2] + smem[3][2];
        double Ci = smem[0][3] + smem[1][3] + smem[2][3] + smem[3][3];
        double D  = smem[0][4] + smem[1][4] + smem[2][4] + smem[3][4];

        const double b2 = G_NOISE;          // g
        const double a2 = 1.0 - G_NOISE;    // 1-g
        double r11 = B / T;                          // rho_11
        double r00 = 1.0 - r11;
        double c2  = (Cr * Cr + Ci * Ci) / (T * T);  // |rho_01|^2
        double det = (r00 + b2 * r11) * (a2 * r11) - a2 * c2;
        double disc = 0.25 - det;
        disc = disc > 0.0 ? sqrt(disc) : 0.0;
        double lp = 0.5 + disc;
        double lm = lp > 0.0 ? det / lp : 0.0;
        double S_out = -(F_pade_d(lp) + F_pade_d(lm));
        double res = -S_out + D / T;                 // -(S(rho_out) - sum coeff*S(sigma))

        out[0] = (float)res;                         // reference output dtype: float
    }
}

extern "C" void kernel_launch(void* const* d_in, const int* in_sizes, int n_in,
                              void* d_out, int out_size, void* d_ws, size_t ws_size,
                              hipStream_t stream) {
    const float*  coeff = (const float*)d_in[0];
    const float4* state = (const float4*)d_in[1];   // 4 floats per sample, 16B aligned
    const int N = in_sizes[0];
    double* partial = (double*)d_ws;                // NBLK*5 doubles = 20480 B

    reduce_kernel<<<NBLK, BLOCK, 0, stream>>>(coeff, state, partial, N);
    final_kernel<<<1, BLOCK, 0, stream>>>(partial, (float*)d_out);
}